// Round 1
// baseline (439.997 us; speedup 1.0000x reference)
//
#include <hip/hip_runtime.h>
#include <hip/hip_bf16.h>
#include <stdint.h>

// Problem constants
#define B_   16
#define H_   112
#define W_   112
#define CIN  128
#define F_   256
#define OH   110
#define OW   110
#define MTOT (B_*OH*OW)        // 193600 output pixels
#define KTOT 1152              // 3*3*128
#define PIX_IN (B_*H_*W_)      // 200704 input pixels
#define D_INV (1.0f/1152.0f)

typedef __bf16 bf16;
typedef __bf16 bf16x8 __attribute__((ext_vector_type(8)));
typedef float  floatx4 __attribute__((ext_vector_type(4)));

typedef __attribute__((address_space(1))) uint32_t guint;
typedef __attribute__((address_space(3))) uint32_t luint;

__device__ __forceinline__ void gld_lds16(const void* g, void* l) {
    __builtin_amdgcn_global_load_lds((guint*)g, (luint*)l, 16, 0, 0);
}

// ws layout:
//   Wst  bf16  [36 ksteps][2 fhalves][4 chunks][128 n][8 j]   = 589824 B
//   S    f32   [PIX_IN]                                       = 802816 B
//   beta f32   [MTOT]                                         = 774400 B
//   xq   bf16  [PIX_IN*CIN]  (optional, prebin path)          = 51380224 B
#define WST_BYTES   589824
#define S_BYTES     802816
#define BETA_BYTES  774400
#define XQ_BYTES    51380224
#define NEED_SMALL  (WST_BYTES + S_BYTES + BETA_BYTES)
#define NEED_FULL   (NEED_SMALL + XQ_BYTES)

// ---------------- prep: W' = sum_e alpha[e,f]*sign(K_e), LDS-image layout ----
__global__ void prep_w(const float* __restrict__ kern, const float* __restrict__ alph,
                       bf16* __restrict__ wst) {
    int idx = blockIdx.x * 256 + threadIdx.x;   // 0..294911 = r*256+f
    int r = idx >> 8, f = idx & 255;
    float w = 0.f;
#pragma unroll
    for (int e = 0; e < 3; ++e) {
        float kv = kern[e * (KTOT * F_) + idx];
        float a  = alph[e * F_ + f];
        w += (__float_as_uint(kv) & 0x80000000u) ? -a : a;
    }
    // r = ks*32 + chunk*8 + j ; f = fh*128 + n
    int ks = r >> 5, chunk = (r >> 3) & 3, j = r & 7;
    int fh = f >> 7, n = f & 127;
    wst[(((ks * 2 + fh) * 512 + chunk * 128 + n) << 3) + j] = (bf16)w;
}

// ---------------- prep: binarize x -> xq (bf16 +-1) and per-pixel sum|x| -----
__global__ void prep_x(const float* __restrict__ x, uint32_t* __restrict__ xq,
                       float* __restrict__ S, int write_xq) {
    int p = blockIdx.x * 4 + (threadIdx.x >> 6);
    int l = threadIdx.x & 63;
    float2 v = ((const float2*)x)[p * 64 + l];
    if (write_xq) {
        uint32_t ba = __float_as_uint(v.x), bb = __float_as_uint(v.y);
        xq[p * 64 + l] = 0x3F803F80u | ((ba & 0x80000000u) >> 16) | (bb & 0x80000000u);
    }
    float s = fabsf(v.x) + fabsf(v.y);
#pragma unroll
    for (int o = 32; o > 0; o >>= 1) s += __shfl_down(s, o, 64);
    if (l == 0) S[p] = s;
}

// ---------------- prep: beta = 3x3 box of S / 1152 ---------------------------
__global__ void prep_beta(const float* __restrict__ S, float* __restrict__ beta) {
    int m = blockIdx.x * 256 + threadIdx.x;
    if (m >= MTOT) return;
    int b = m / (OH * OW); int r = m - b * (OH * OW);
    int oi = r / OW, oj = r - oi * OW;
    const float* sp = S + (b * H_ + oi) * W_ + oj;
    float acc = 0.f;
#pragma unroll
    for (int dh = 0; dh < 3; ++dh)
#pragma unroll
        for (int dw = 0; dw < 3; ++dw) acc += sp[dh * W_ + dw];
    beta[m] = acc * D_INV;
}

__device__ __forceinline__ uint32_t pack2sign(float a, float b) {
    return 0x3F803F80u | ((__float_as_uint(a) & 0x80000000u) >> 16)
                       | (__float_as_uint(b) & 0x80000000u);
}

// ---------------- main: implicit GEMM, 128x128 tile, 16x16x32 bf16 MFMA ------
template <bool PREBIN>
__global__ __launch_bounds__(256)
void conv_main(const void* __restrict__ xin, const bf16* __restrict__ wst,
               const float* __restrict__ beta, float* __restrict__ out) {
    __shared__ char smem[16384];   // A: [4 chunk][128 row][16B], B: same at +8192

    const int t = threadIdx.x;
    const int l = t & 63, wv = t >> 6;
    const int quad = l >> 4, lane16 = l & 15;
    const int wm = wv >> 1, wn = wv & 1;
    const int f0 = blockIdx.x * 128;
    const int m0 = blockIdx.y * 128;

    // staging roles: for q in {0,1}: idx=q*256+t ; chunk=idx>>7 ; rn=idx&127
    const char* a_base[2];
    const char* b_base[2];
#pragma unroll
    for (int q = 0; q < 2; ++q) {
        int idx = q * 256 + t;
        int chunk = idx >> 7, rn = idx & 127;
        int m = m0 + rn; if (m >= MTOT) m = MTOT - 1;
        int b = m / (OH * OW); int rr = m - b * (OH * OW);
        int oi = rr / OW, oj = rr - oi * OW;
        long pix = ((long)(b * H_ + oi) * W_ + oj) * CIN;
        a_base[q] = (const char*)xin + (PREBIN ? (pix + chunk * 8) * 2
                                               : (pix + chunk * 8) * 4);
        b_base[q] = (const char*)(wst + (long)blockIdx.x * 4096) + idx * 16; // fh offset in elems*2B: fh*512*16B
    }

    floatx4 acc[4][4];
#pragma unroll
    for (int a = 0; a < 4; ++a)
#pragma unroll
        for (int bb = 0; bb < 4; ++bb) acc[a][bb] = (floatx4){0.f, 0.f, 0.f, 0.f};

    for (int ks = 0; ks < 36; ++ks) {
        int kh = ks / 12, kw = (ks % 12) / 4, c0 = (ks & 3) * 32;
        int aoff = (kh * W_ + kw) * CIN + c0;   // element offset from pixel base
#pragma unroll
        for (int q = 0; q < 2; ++q) {
            int idx = q * 256 + t;
            if (PREBIN) {
                gld_lds16(a_base[q] + (long)aoff * 2, smem + idx * 16);
            } else {
                const float4* src = (const float4*)(a_base[q] + (long)aoff * 4);
                float4 v0 = src[0], v1 = src[1];
                uint4 pv = make_uint4(pack2sign(v0.x, v0.y), pack2sign(v0.z, v0.w),
                                      pack2sign(v1.x, v1.y), pack2sign(v1.z, v1.w));
                *(uint4*)(smem + idx * 16) = pv;
            }
            // B: ws image is [ks][fh][512 chunks of 16B]; fh folded into b_base
            gld_lds16(b_base[q] + (long)ks * 16384, smem + 8192 + idx * 16);
        }
        __syncthreads();

        bf16x8 af[4], bfr[4];
#pragma unroll
        for (int tm = 0; tm < 4; ++tm) {
            int row = wm * 64 + tm * 16 + lane16;
            af[tm] = *(const bf16x8*)(smem + quad * 2048 + row * 16);
        }
#pragma unroll
        for (int tn = 0; tn < 4; ++tn) {
            int col = wn * 64 + tn * 16 + lane16;
            bfr[tn] = *(const bf16x8*)(smem + 8192 + quad * 2048 + col * 16);
        }
#pragma unroll
        for (int tm = 0; tm < 4; ++tm)
#pragma unroll
            for (int tn = 0; tn < 4; ++tn)
                acc[tm][tn] = __builtin_amdgcn_mfma_f32_16x16x32_bf16(
                    af[tm], bfr[tn], acc[tm][tn], 0, 0, 0);
        __syncthreads();
    }

    // epilogue: out[m,f] = beta[m] * acc
#pragma unroll
    for (int tm = 0; tm < 4; ++tm) {
#pragma unroll
        for (int i = 0; i < 4; ++i) {
            int m = m0 + wm * 64 + tm * 16 + quad * 4 + i;
            if (m < MTOT) {
                float bv = beta[m];
                float* op = out + (long)m * F_ + f0 + wn * 64 + lane16;
#pragma unroll
                for (int tn = 0; tn < 4; ++tn)
                    op[tn * 16] = acc[tm][tn][i] * bv;
            }
        }
    }
}

extern "C" void kernel_launch(void* const* d_in, const int* in_sizes, int n_in,
                              void* d_out, int out_size, void* d_ws, size_t ws_size,
                              hipStream_t stream) {
    const float* x    = (const float*)d_in[0];
    const float* kern = (const float*)d_in[1];
    const float* alph = (const float*)d_in[2];
    float* out = (float*)d_out;
    char* ws = (char*)d_ws;

    bf16*  wst  = (bf16*)ws;
    float* S    = (float*)(ws + WST_BYTES);
    float* beta = (float*)(ws + WST_BYTES + S_BYTES);
    char*  xq   = ws + NEED_SMALL;
    bool prebin = ws_size >= (size_t)NEED_FULL;

    hipLaunchKernelGGL(prep_w, dim3(KTOT * F_ / 256), dim3(256), 0, stream, kern, alph, wst);
    hipLaunchKernelGGL(prep_x, dim3(PIX_IN / 4), dim3(256), 0, stream,
                       x, (uint32_t*)xq, S, (int)prebin);
    hipLaunchKernelGGL(prep_beta, dim3((MTOT + 255) / 256), dim3(256), 0, stream, S, beta);

    dim3 grid(2, (MTOT + 127) / 128);  // f-halves x m-tiles
    if (prebin)
        hipLaunchKernelGGL(conv_main<true>, grid, dim3(256), 0, stream,
                           (const void*)xq, wst, beta, out);
    else
        hipLaunchKernelGGL(conv_main<false>, grid, dim3(256), 0, stream,
                           (const void*)x, wst, beta, out);
}

// Round 2
// 352.153 us; speedup vs baseline: 1.2494x; 1.2494x over previous
//
#include <hip/hip_runtime.h>
#include <hip/hip_bf16.h>
#include <stdint.h>

// Problem constants
#define B_   16
#define H_   112
#define W_   112
#define CIN  128
#define F_   256
#define OH   110
#define OW   110
#define MTOT (B_*OH*OW)        // 193600 output pixels
#define KTOT 1152              // 3*3*128
#define PIX_IN (B_*H_*W_)      // 200704 input pixels
#define D_INV (1.0f/1152.0f)

typedef float floatx4 __attribute__((ext_vector_type(4)));
typedef int   intx4   __attribute__((ext_vector_type(4)));

typedef __attribute__((address_space(1))) uint32_t guint;
typedef __attribute__((address_space(3))) uint32_t luint;

__device__ __forceinline__ void gld_lds16(const void* g, void* l) {
    __builtin_amdgcn_global_load_lds((guint*)g, (luint*)l, 16, 0, 0);
}

// ws layout (bytes):
//   wst  i8   [18 ks][2 fh][4 chunk][128 n][16 j]  = 294912
//   sf   f32  [256]                                = 1024
//   S    f32  [PIX_IN]                             = 802816
//   beta f32  [MTOT]                               = 774400
//   xq   i8   [PIX_IN*CIN]                         = 25690112
#define WST_OFF   0
#define SF_OFF    294912
#define S_OFF     295936
#define BETA_OFF  1098752
#define XQ_OFF    1873152
#define NEED_FULL (XQ_OFF + (size_t)PIX_IN*CIN)

// ---- prep: W' = sum_e alpha[e,f]*sign(K_e); quantize i8 with s_f ----------
__global__ void prep_wq(const float* __restrict__ kern, const float* __restrict__ alph,
                        int8_t* __restrict__ wst, float* __restrict__ sf) {
    int idx = blockIdx.x * 256 + threadIdx.x;   // = r*256 + f
    int r = idx >> 8, f = idx & 255;
    float a0 = alph[f], a1 = alph[256 + f], a2 = alph[512 + f];  // >= 0
    float w = 0.f;
    float kv0 = kern[idx], kv1 = kern[294912 + idx], kv2 = kern[589824 + idx];
    w += (__float_as_uint(kv0) & 0x80000000u) ? -a0 : a0;
    w += (__float_as_uint(kv1) & 0x80000000u) ? -a1 : a1;
    w += (__float_as_uint(kv2) & 0x80000000u) ? -a2 : a2;
    float s = (a0 + a1 + a2) * (1.0f / 127.0f);          // bounds |w| -> |q|<=127
    int q = (int)__builtin_rintf(w / s);
    // image addr: [ks=r>>6][fh=f>>7][chunk=(r>>4)&3][n=f&127][j=r&15]
    wst[((((r >> 6) * 2 + (f >> 7)) * 4 + ((r >> 4) & 3)) * 128 + (f & 127)) * 16 + (r & 15)]
        = (int8_t)q;
    if (r == 0) sf[f] = s;
}

// ---- prep: binarize x -> xq (i8 +-1), per-pixel sum|x| --------------------
__device__ __forceinline__ uint32_t pack4sign(float4 v) {
    uint32_t b0 = ((__float_as_uint(v.x) >> 31) * 0xFEu) ^ 0x01u;
    uint32_t b1 = ((__float_as_uint(v.y) >> 31) * 0xFEu) ^ 0x01u;
    uint32_t b2 = ((__float_as_uint(v.z) >> 31) * 0xFEu) ^ 0x01u;
    uint32_t b3 = ((__float_as_uint(v.w) >> 31) * 0xFEu) ^ 0x01u;
    return b0 | (b1 << 8) | (b2 << 16) | (b3 << 24);
}

__global__ void prep_x(const float* __restrict__ x, uint32_t* __restrict__ xq,
                       float* __restrict__ S, int write_xq) {
    int idx = blockIdx.x * 256 + threadIdx.x;   // float4 index; 32 per pixel
    float4 v = ((const float4*)x)[idx];
    if (write_xq) xq[idx] = pack4sign(v);
    float s = fabsf(v.x) + fabsf(v.y) + fabsf(v.z) + fabsf(v.w);
#pragma unroll
    for (int o = 1; o < 32; o <<= 1) s += __shfl_xor(s, o, 64);  // within 32-group
    if ((threadIdx.x & 31) == 0) S[idx >> 5] = s;
}

// ---- prep: beta = 3x3 box of S / 1152 -------------------------------------
__global__ void prep_beta(const float* __restrict__ S, float* __restrict__ beta) {
    int m = blockIdx.x * 256 + threadIdx.x;
    if (m >= MTOT) return;
    int b = m / (OH * OW); int r = m - b * (OH * OW);
    int oi = r / OW, oj = r - oi * OW;
    const float* sp = S + (b * H_ + oi) * W_ + oj;
    float acc = 0.f;
#pragma unroll
    for (int dh = 0; dh < 3; ++dh)
#pragma unroll
        for (int dw = 0; dw < 3; ++dw) acc += sp[dh * W_ + dw];
    beta[m] = acc * D_INV;
}

// ---- main: implicit GEMM, 128x128 tile, 16x16x64 i8 MFMA, BK=64 -----------
template <bool PREBIN>
__global__ __launch_bounds__(256)
void conv_main(const void* __restrict__ xin, const int8_t* __restrict__ wst,
               const float* __restrict__ sf, const float* __restrict__ beta,
               float* __restrict__ out) {
    __shared__ char smem[16384];   // A: [4 chunk(k16)][128 row][16B]; B same at +8192

    const int t = threadIdx.x;
    const int l = t & 63, wv = t >> 6;
    const int quad = l >> 4, lane16 = l & 15;
    const int wm = wv >> 1, wn = wv & 1;
    const int f0 = blockIdx.x * 128;
    const int m0 = blockIdx.y * 128;

    const char* a_base[2];
    const char* b_base[2];
#pragma unroll
    for (int q = 0; q < 2; ++q) {
        int idx = q * 256 + t;
        int chunk = idx >> 7, rn = idx & 127;
        int m = m0 + rn; if (m >= MTOT) m = MTOT - 1;
        int b = m / (OH * OW); int rr = m - b * (OH * OW);
        int oi = rr / OW, oj = rr - oi * OW;
        long pix = ((long)(b * H_ + oi) * W_ + oj) * CIN;  // element index
        a_base[q] = (const char*)xin + (PREBIN ? (pix + chunk * 16)       // 1 B/elem
                                               : (pix + chunk * 16) * 4); // 4 B/elem
        b_base[q] = (const char*)wst + blockIdx.x * 8192 + idx * 16;
    }

    intx4 acc[4][4];
#pragma unroll
    for (int a = 0; a < 4; ++a)
#pragma unroll
        for (int bb = 0; bb < 4; ++bb) acc[a][bb] = (intx4){0, 0, 0, 0};

    for (int ks = 0; ks < 18; ++ks) {
        int kh = ks / 6, rem = ks - kh * 6;
        int kw = rem >> 1, c0 = (rem & 1) << 6;
        int aoff = (kh * W_ + kw) * CIN + c0;   // element offset from pixel base
#pragma unroll
        for (int q = 0; q < 2; ++q) {
            int idx = q * 256 + t;
            if (PREBIN) {
                gld_lds16(a_base[q] + aoff, smem + idx * 16);
            } else {
                const float4* src = (const float4*)(a_base[q] + (long)aoff * 4);
                float4 v0 = src[0], v1 = src[1], v2 = src[2], v3 = src[3];
                uint4 pv = make_uint4(pack4sign(v0), pack4sign(v1),
                                      pack4sign(v2), pack4sign(v3));
                *(uint4*)(smem + idx * 16) = pv;
            }
            gld_lds16(b_base[q] + (long)ks * 16384, smem + 8192 + idx * 16);
        }
        __syncthreads();

        intx4 af[4], bf[4];
#pragma unroll
        for (int tm = 0; tm < 4; ++tm) {
            int row = wm * 64 + tm * 16 + lane16;
            af[tm] = *(const intx4*)(smem + quad * 2048 + row * 16);
        }
#pragma unroll
        for (int tn = 0; tn < 4; ++tn) {
            int col = wn * 64 + tn * 16 + lane16;
            bf[tn] = *(const intx4*)(smem + 8192 + quad * 2048 + col * 16);
        }
#pragma unroll
        for (int tm = 0; tm < 4; ++tm)
#pragma unroll
            for (int tn = 0; tn < 4; ++tn)
                acc[tm][tn] = __builtin_amdgcn_mfma_i32_16x16x64_i8(
                    af[tm], bf[tn], acc[tm][tn], 0, 0, 0);
        __syncthreads();
    }

    // epilogue: out[m,f] = beta[m] * sf[f] * acc
    float sv[4];
#pragma unroll
    for (int tn = 0; tn < 4; ++tn) sv[tn] = sf[f0 + wn * 64 + tn * 16 + lane16];

#pragma unroll
    for (int tm = 0; tm < 4; ++tm) {
#pragma unroll
        for (int i = 0; i < 4; ++i) {
            int m = m0 + wm * 64 + tm * 16 + quad * 4 + i;
            if (m < MTOT) {
                float bv = beta[m];
                float* op = out + (long)m * F_ + f0 + wn * 64 + lane16;
#pragma unroll
                for (int tn = 0; tn < 4; ++tn)
                    op[tn * 16] = (float)acc[tm][tn][i] * (bv * sv[tn]);
            }
        }
    }
}

extern "C" void kernel_launch(void* const* d_in, const int* in_sizes, int n_in,
                              void* d_out, int out_size, void* d_ws, size_t ws_size,
                              hipStream_t stream) {
    const float* x    = (const float*)d_in[0];
    const float* kern = (const float*)d_in[1];
    const float* alph = (const float*)d_in[2];
    float* out = (float*)d_out;
    char* ws = (char*)d_ws;

    int8_t* wst  = (int8_t*)(ws + WST_OFF);
    float*  sf   = (float*)(ws + SF_OFF);
    float*  S    = (float*)(ws + S_OFF);
    float*  beta = (float*)(ws + BETA_OFF);
    char*   xq   = ws + XQ_OFF;
    bool prebin = ws_size >= NEED_FULL;

    hipLaunchKernelGGL(prep_wq, dim3(KTOT * F_ / 256), dim3(256), 0, stream,
                       kern, alph, wst, sf);
    hipLaunchKernelGGL(prep_x, dim3(PIX_IN * CIN / 4 / 256), dim3(256), 0, stream,
                       x, (uint32_t*)xq, S, (int)prebin);
    hipLaunchKernelGGL(prep_beta, dim3((MTOT + 255) / 256), dim3(256), 0, stream, S, beta);

    dim3 grid(2, (MTOT + 127) / 128);  // f-halves x m-tiles
    if (prebin)
        hipLaunchKernelGGL(conv_main<true>, grid, dim3(256), 0, stream,
                           (const void*)xq, wst, sf, beta, out);
    else
        hipLaunchKernelGGL(conv_main<false>, grid, dim3(256), 0, stream,
                           (const void*)x, wst, sf, beta, out);
}